// Round 6
// baseline (261.649 us; speedup 1.0000x reference)
//
#include <hip/hip_runtime.h>
#include <stdint.h>

#define THRESH 1.5f
constexpr int NPIX = 8 * 1024 * 1024;   // 2^23 pixels
constexpr int HW   = 1024 * 1024;       // pixels per image
constexpr int WW   = 1024;              // image width
constexpr int NWORD = NPIX / 32;        // 262144 mask words (32 px each)
constexpr int WPR   = WW / 32;          // 32 words per image row

constexpr int BLK     = 256;
constexpr int GRD_PX4 = NPIX / (BLK * 4);  // 8192 blocks (4 px/thread)
constexpr int GRD_W   = NWORD / BLK;       // 1024 blocks (1 word/thread)

// ---------------------------------------------------------------------------
// Plain union-find over pixel ids; parent[i] < NPIX always, root <=> self.
// (Round-5 post-mortem: ws_size = 384 MiB — the compact-id/claim pass existed
// only to shrink stats arrays below a 64 MiB ws that never was. Dense
// root-indexed cnt/best (100 MB) removes a dispatch and an indirection.)
// ---------------------------------------------------------------------------
__device__ __forceinline__ int find_root(const int* __restrict__ P, int x) {
    int p = P[x];
    while (p != x) { x = p; p = P[x]; }
    return x;
}

__device__ __forceinline__ void merge(int* P, int a, int b) {
    int ra = find_root(P, a);
    int rb = find_root(P, b);
    while (ra != rb) {
        if (ra < rb) { int t = ra; ra = rb; rb = t; }   // ra > rb
        int old = atomicCAS(&P[ra], ra, rb);            // link larger -> smaller
        if (old == ra) break;
        ra = find_root(P, old);
        rb = find_root(P, rb);
    }
}

// Pass 1: read x once (float4), build fg bitmask, init parent, and zero
// cnt/best for fg quads only (~24% of quads) — replaces any dense init pass.
__global__ void mask_init_k(const float* __restrict__ x, int* __restrict__ parent,
                            unsigned* __restrict__ mask, int* __restrict__ cnt,
                            unsigned long long* __restrict__ best) {
    __shared__ unsigned s_nib[BLK];
    int t  = threadIdx.x;
    int gt = blockIdx.x * BLK + t;
    int i4 = gt * 4;
    float4 v = *(const float4*)(x + i4);
    unsigned nib = (unsigned)(v.x >= THRESH) | ((unsigned)(v.y >= THRESH) << 1) |
                   ((unsigned)(v.z >= THRESH) << 2) | ((unsigned)(v.w >= THRESH) << 3);
    *(int4*)(parent + i4) = make_int4(i4, i4 + 1, i4 + 2, i4 + 3);
    if (nib) {
        *(int4*)(cnt + i4) = make_int4(0, 0, 0, 0);
        ((ulonglong2*)(best + i4))[0] = make_ulonglong2(0ull, 0ull);
        ((ulonglong2*)(best + i4))[1] = make_ulonglong2(0ull, 0ull);
    }
    s_nib[t] = nib;
    __syncthreads();
    if ((t & 7) == 0) {
        unsigned w = 0;
        #pragma unroll
        for (int k = 0; k < 8; k++) w |= s_nib[t + k] << (4 * k);
        mask[gt >> 3] = w;
    }
}

// Pass 2: per-WORD union (32 px/thread); neighbor tests are bit-ops on the
// mask, only true 8-adjacency edges (~150k) touch parent.
__global__ void union_k(const unsigned* __restrict__ mask, int* __restrict__ parent) {
    int w = blockIdx.x * BLK + threadIdx.x;
    unsigned cur = mask[w];
    if (!cur) return;
    int r  = (w >> 5) & (WW - 1);   // row within image (words never cross rows)
    int cw = w & (WPR - 1);         // word-column within row
    unsigned prev = (cw > 0) ? mask[w - 1] : 0u;
    unsigned above = 0u, abovePrev = 0u, aboveNext = 0u;
    if (r > 0) {
        above     = mask[w - WPR];
        abovePrev = (cw > 0)       ? mask[w - WPR - 1] : 0u;
        aboveNext = (cw < WPR - 1) ? mask[w - WPR + 1] : 0u;
    }
    int base = w << 5;
    unsigned mW  = cur & ((cur   << 1) | (prev      >> 31));
    unsigned mN  = cur & above;
    unsigned mNW = cur & ((above << 1) | (abovePrev >> 31));
    unsigned mNE = cur & ((above >> 1) | ((aboveNext & 1u) << 31));
    while (mW)  { int b = __ffs(mW)  - 1; mW  &= mW  - 1; merge(parent, base + b, base + b - 1); }
    while (mN)  { int b = __ffs(mN)  - 1; mN  &= mN  - 1; merge(parent, base + b, base + b - WW); }
    while (mNW) { int b = __ffs(mNW) - 1; mNW &= mNW - 1; merge(parent, base + b, base + b - WW - 1); }
    while (mNE) { int b = __ffs(mNE) - 1; mNE &= mNE - 1; merge(parent, base + b, base + b - WW + 1); }
}

// Pass 3 (fused old claim+stats): per fg pixel — find root, fully compress
// parent (out_k then needs exactly one hop), root-indexed area count and
// fused (max value, min index of max) via one 64-bit atomicMax on
// (float_bits << 32) | ~within_index.
__device__ __forceinline__ void stat_one(int* __restrict__ parent,
                                         int* __restrict__ cnt,
                                         unsigned long long* __restrict__ best,
                                         int p, float v) {
    int r = find_root(parent, p);
    if (r != p) parent[p] = r;
    atomicAdd(&cnt[r], 1);
    unsigned within = (unsigned)(p & (HW - 1));
    unsigned long long pk =
        ((unsigned long long)__float_as_uint(v) << 32) |
        (unsigned long long)(~within);
    atomicMax(&best[r], pk);
}

__global__ void stats_k(const float* __restrict__ x, const unsigned* __restrict__ mask,
                        int* __restrict__ parent, int* __restrict__ cnt,
                        unsigned long long* __restrict__ best) {
    int t = blockIdx.x * BLK + threadIdx.x;
    unsigned nib = (mask[t >> 3] >> ((t & 7) * 4)) & 0xFu;
    if (!nib) return;
    int i4 = t * 4;
    float4 v = *(const float4*)(x + i4);
    if (nib & 1u) stat_one(parent, cnt, best, i4,     v.x);
    if (nib & 2u) stat_one(parent, cnt, best, i4 + 1, v.y);
    if (nib & 4u) stat_one(parent, cnt, best, i4 + 2, v.z);
    if (nib & 8u) stat_one(parent, cnt, best, i4 + 3, v.w);
}

// Pass 4: emit float32 planes (max,row,col) with float4 stores; one-hop root.
__device__ __forceinline__ void lookup_one(const int* __restrict__ parent,
                                           const int* __restrict__ cnt,
                                           const unsigned long long* __restrict__ best,
                                           int p, float& om, float& orow, float& ocol) {
    int r = parent[p];                                 // compressed by stats_k
    if (cnt[r] > 3) {                                  // area > MIN_AREA
        unsigned long long pk = best[r];
        om   = __uint_as_float((unsigned)(pk >> 32));
        unsigned idx = ~((unsigned)pk);                // within-image flat idx
        orow = (float)(idx >> 10);
        ocol = (float)(idx & (WW - 1));
    }
}

__global__ void out_k(const unsigned* __restrict__ mask, const int* __restrict__ parent,
                      const int* __restrict__ cnt,
                      const unsigned long long* __restrict__ best,
                      float* __restrict__ o) {
    int t = blockIdx.x * BLK + threadIdx.x;
    unsigned nib = (mask[t >> 3] >> ((t & 7) * 4)) & 0xFu;
    int i4 = t * 4;
    float4 m  = make_float4(0.f, 0.f, 0.f, 0.f);
    float4 rr = make_float4(-1.f, -1.f, -1.f, -1.f);
    float4 cc = make_float4(-1.f, -1.f, -1.f, -1.f);
    if (nib) {
        if (nib & 1u) lookup_one(parent, cnt, best, i4,     m.x, rr.x, cc.x);
        if (nib & 2u) lookup_one(parent, cnt, best, i4 + 1, m.y, rr.y, cc.y);
        if (nib & 4u) lookup_one(parent, cnt, best, i4 + 2, m.z, rr.z, cc.z);
        if (nib & 8u) lookup_one(parent, cnt, best, i4 + 3, m.w, rr.w, cc.w);
    }
    *(float4*)(o + i4)            = m;
    *(float4*)(o + NPIX + i4)     = rr;
    *(float4*)(o + 2 * NPIX + i4) = cc;
}

// ---------------------------------------------------------------------------
extern "C" void kernel_launch(void* const* d_in, const int* in_sizes, int n_in,
                              void* d_out, int out_size, void* d_ws, size_t ws_size,
                              hipStream_t stream) {
    const float* x = (const float*)d_in[0];
    float* o = (float*)d_out;

    // ws layout (dense, root-indexed; ws_size = 384 MiB per round-5 fill
    // evidence): parent i32[NPIX] 33.5MB | best u64[NPIX] 67MB |
    // cnt i32[NPIX] 33.5MB | mask u32[NWORD] 1MB. Total ~135MB.
    char* base = (char*)d_ws;
    int* parent = (int*)base;
    unsigned long long* best = (unsigned long long*)(base + (size_t)NPIX * 4);
    int* cnt       = (int*)(base + (size_t)NPIX * 12);
    unsigned* mask = (unsigned*)(base + (size_t)NPIX * 16);

    mask_init_k<<<GRD_PX4, BLK, 0, stream>>>(x, parent, mask, cnt, best);
    union_k    <<<GRD_W,   BLK, 0, stream>>>(mask, parent);
    stats_k    <<<GRD_PX4, BLK, 0, stream>>>(x, mask, parent, cnt, best);
    out_k      <<<GRD_PX4, BLK, 0, stream>>>(mask, parent, cnt, best, o);
}

// Round 7
// 202.881 us; speedup vs baseline: 1.2897x; 1.2897x over previous
//
#include <hip/hip_runtime.h>
#include <stdint.h>

#define THRESH 1.5f
constexpr int NPIX = 8 * 1024 * 1024;   // 2^23 pixels
constexpr int HW   = 1024 * 1024;       // pixels per image
constexpr int WW   = 1024;              // image width
constexpr int NWORD = NPIX / 32;        // 262144 mask words
constexpr int WPR   = WW / 32;          // 32 words per image row

constexpr int BLK     = 256;
constexpr int GRD_PX4 = NPIX / (BLK * 4);  // 8192 blocks (4 px/thread; 1024 px/block)
constexpr int GRD_W   = NWORD / BLK;       // 1024 blocks (1 word/thread)

// compact claim slots (round-6 post-mortem: compact 8MB stats region >> dense
// 100MB — locality of the atomic/lookup arrays beats saving a dispatch)
constexpr int SPB        = 640;            // slots per claim block (E~406, 11 sigma)
constexpr int BASE_SLOTS = GRD_W * SPB;    // 655360
constexpr int OVF_SLOTS  = 16384;
constexpr int CAP        = BASE_SLOTS + OVF_SLOTS;

constexpr int WLSTRIDE = 1024;             // worklist entries per mask_init block

// ---------------------------------------------------------------------------
// parent[] encoding: < NPIX = union-find pointer (self <=> unclaimed root);
//                   >= NPIX = claimed root, compact id = value - NPIX.
// ---------------------------------------------------------------------------
__device__ __forceinline__ int find_root(const int* __restrict__ P, int x) {
    int p = P[x];
    while (p != x && p < NPIX) { x = p; p = P[x]; }
    return x;
}

__device__ __forceinline__ void merge(int* P, int a, int b) {
    int ra = find_root(P, a);
    int rb = find_root(P, b);
    while (ra != rb) {
        if (ra < rb) { int t = ra; ra = rb; rb = t; }   // ra > rb
        int old = atomicCAS(&P[ra], ra, rb);            // link larger -> smaller
        if (old == ra) break;
        ra = find_root(P, old);
        rb = find_root(P, rb);
    }
}

// Pass 1: read x once (float4), build fg bitmask, init parent, and append
// (pixel_id, value_bits) for every fg pixel into this block's worklist region
// (LDS-ranked; deterministic per-block slots, no global counter).
__global__ void mask_init_k(const float* __restrict__ x, int* __restrict__ parent,
                            unsigned* __restrict__ mask, uint2* __restrict__ wl,
                            int* __restrict__ wl_cnt, int* __restrict__ ovf) {
    __shared__ unsigned s_nib[BLK];
    __shared__ int s_rank;
    int t  = threadIdx.x;
    int gt = blockIdx.x * BLK + t;
    int i4 = gt * 4;
    float4 v = *(const float4*)(x + i4);
    unsigned nib = (unsigned)(v.x >= THRESH) | ((unsigned)(v.y >= THRESH) << 1) |
                   ((unsigned)(v.z >= THRESH) << 2) | ((unsigned)(v.w >= THRESH) << 3);
    *(int4*)(parent + i4) = make_int4(i4, i4 + 1, i4 + 2, i4 + 3);
    if (t == 0) s_rank = 0;
    s_nib[t] = nib;
    __syncthreads();
    if ((t & 7) == 0) {
        unsigned w = 0;
        #pragma unroll
        for (int k = 0; k < 8; k++) w |= s_nib[t + k] << (4 * k);
        mask[gt >> 3] = w;
    }
    int nfg = __popc(nib);
    if (nfg) {
        int r = atomicAdd(&s_rank, nfg);                // LDS atomic
        uint2* dst = wl + (size_t)blockIdx.x * WLSTRIDE;
        if (nib & 1u) dst[r++] = make_uint2((unsigned)i4,     __float_as_uint(v.x));
        if (nib & 2u) dst[r++] = make_uint2((unsigned)i4 + 1, __float_as_uint(v.y));
        if (nib & 4u) dst[r++] = make_uint2((unsigned)i4 + 2, __float_as_uint(v.z));
        if (nib & 8u) dst[r++] = make_uint2((unsigned)i4 + 3, __float_as_uint(v.w));
    }
    __syncthreads();
    if (t == 0) wl_cnt[blockIdx.x] = s_rank;
    if (gt == 0) *ovf = 0;
}

// Pass 2: per-WORD union (32 px/thread); neighbor tests are bit-ops on the
// mask, only true 8-adjacency edges (~150k) touch parent.
__global__ void union_k(const unsigned* __restrict__ mask, int* __restrict__ parent) {
    int w = blockIdx.x * BLK + threadIdx.x;
    unsigned cur = mask[w];
    if (!cur) return;
    int r  = (w >> 5) & (WW - 1);   // row within image (words never cross rows)
    int cw = w & (WPR - 1);         // word-column within row
    unsigned prev = (cw > 0) ? mask[w - 1] : 0u;
    unsigned above = 0u, abovePrev = 0u, aboveNext = 0u;
    if (r > 0) {
        above     = mask[w - WPR];
        abovePrev = (cw > 0)       ? mask[w - WPR - 1] : 0u;
        aboveNext = (cw < WPR - 1) ? mask[w - WPR + 1] : 0u;
    }
    int base = w << 5;
    unsigned mW  = cur & ((cur   << 1) | (prev      >> 31));
    unsigned mN  = cur & above;
    unsigned mNW = cur & ((above << 1) | (abovePrev >> 31));
    unsigned mNE = cur & ((above >> 1) | ((aboveNext & 1u) << 31));
    while (mW)  { int b = __ffs(mW)  - 1; mW  &= mW  - 1; merge(parent, base + b, base + b - 1); }
    while (mN)  { int b = __ffs(mN)  - 1; mN  &= mN  - 1; merge(parent, base + b, base + b - WW); }
    while (mNW) { int b = __ffs(mNW) - 1; mNW &= mNW - 1; merge(parent, base + b, base + b - WW - 1); }
    while (mNE) { int b = __ffs(mNE) - 1; mNE &= mNE - 1; merge(parent, base + b, base + b - WW + 1); }
}

// Pass 3: per-word compress every fg pixel + deterministic per-block slot
// claim; the claimer zero-inits its slot's cnt/best.
__global__ void claim_k(const unsigned* __restrict__ mask, int* __restrict__ parent,
                        int* __restrict__ cnt, unsigned long long* __restrict__ best,
                        int* __restrict__ ovf) {
    __shared__ int s_cnt;
    if (threadIdx.x == 0) s_cnt = 0;
    __syncthreads();
    int w = blockIdx.x * BLK + threadIdx.x;
    unsigned cur = mask[w];
    int base = w << 5;
    while (cur) {
        int b = __ffs(cur) - 1; cur &= cur - 1;
        int p = base + b;
        int root = find_root(parent, p);
        if (root == p) {
            int rank = atomicAdd(&s_cnt, 1);    // LDS atomic
            int slot;
            if (rank < SPB) slot = blockIdx.x * SPB + rank;
            else { int o = atomicAdd(ovf, 1); slot = BASE_SLOTS + (o < OVF_SLOTS ? o : OVF_SLOTS - 1); }
            cnt[slot] = 0; best[slot] = 0ull;
            parent[p] = NPIX + slot;
        } else {
            parent[p] = root;                   // full path compression
        }
    }
}

__device__ __forceinline__ int compact_id(const int* __restrict__ P, int p) {
    int e = P[p];                // direct root ptr or own claim
    if (e < NPIX) e = P[e];      // root's claim (>= NPIX after claim_k)
    return e - NPIX;
}

// Pass 4: stats over the WORKLIST — one wave per mask_init block region
// (~68 avg entries), fully-active lanes, coalesced 8B reads, no x/mask
// re-read. Area count + fused (max value, min index of max) via one 64-bit
// atomicMax on (float_bits << 32) | ~within_index.
__global__ void stats_k(const uint2* __restrict__ wl, const int* __restrict__ wl_cnt,
                        const int* __restrict__ parent, int* __restrict__ cnt,
                        unsigned long long* __restrict__ best) {
    int region = blockIdx.x;
    int c = wl_cnt[region];
    const uint2* src = wl + (size_t)region * WLSTRIDE;
    for (int j = threadIdx.x; j < c; j += 64) {
        uint2 e = src[j];
        int p = (int)e.x;
        int cid = compact_id(parent, p);
        if (cid < 0 || cid >= CAP) continue;
        atomicAdd(&cnt[cid], 1);
        unsigned within = (unsigned)(p & (HW - 1));
        unsigned long long pk =
            ((unsigned long long)e.y << 32) | (unsigned long long)(~within);
        atomicMax(&best[cid], pk);
    }
}

// Pass 5: emit float32 planes (max,row,col) with float4 stores.
__device__ __forceinline__ void lookup_one(const int* __restrict__ parent,
                                           const int* __restrict__ cnt,
                                           const unsigned long long* __restrict__ best,
                                           int p, float& om, float& orow, float& ocol) {
    int cid = compact_id(parent, p);
    if (cid >= 0 && cid < CAP && cnt[cid] > 3) {       // area > MIN_AREA
        unsigned long long pk = best[cid];
        om   = __uint_as_float((unsigned)(pk >> 32));
        unsigned idx = ~((unsigned)pk);                // within-image flat idx
        orow = (float)(idx >> 10);
        ocol = (float)(idx & (WW - 1));
    }
}

__global__ void out_k(const unsigned* __restrict__ mask, const int* __restrict__ parent,
                      const int* __restrict__ cnt,
                      const unsigned long long* __restrict__ best,
                      float* __restrict__ o) {
    int t = blockIdx.x * BLK + threadIdx.x;
    unsigned nib = (mask[t >> 3] >> ((t & 7) * 4)) & 0xFu;
    int i4 = t * 4;
    float4 m  = make_float4(0.f, 0.f, 0.f, 0.f);
    float4 rr = make_float4(-1.f, -1.f, -1.f, -1.f);
    float4 cc = make_float4(-1.f, -1.f, -1.f, -1.f);
    if (nib) {
        if (nib & 1u) lookup_one(parent, cnt, best, i4,     m.x, rr.x, cc.x);
        if (nib & 2u) lookup_one(parent, cnt, best, i4 + 1, m.y, rr.y, cc.y);
        if (nib & 4u) lookup_one(parent, cnt, best, i4 + 2, m.z, rr.z, cc.z);
        if (nib & 8u) lookup_one(parent, cnt, best, i4 + 3, m.w, rr.w, cc.w);
    }
    *(float4*)(o + i4)            = m;
    *(float4*)(o + NPIX + i4)     = rr;
    *(float4*)(o + 2 * NPIX + i4) = cc;
}

// ---------------------------------------------------------------------------
extern "C" void kernel_launch(void* const* d_in, const int* in_sizes, int n_in,
                              void* d_out, int out_size, void* d_ws, size_t ws_size,
                              hipStream_t stream) {
    const float* x = (const float*)d_in[0];
    float* o = (float*)d_out;

    // ws layout (384 MiB available): parent i32[NPIX] 33.5MB | best u64[CAP]
    // 5.4MB | cnt i32[CAP] 2.7MB | mask u32[NWORD] 1MB | wl_cnt i32[8192] |
    // wl uint2[8192*1024] 67MB | ovf. Total ~110MB.
    char* base = (char*)d_ws;
    int* parent = (int*)base;
    size_t off = (size_t)NPIX * 4;
    unsigned long long* best = (unsigned long long*)(base + off);  off += (size_t)CAP * 8;
    int* cnt       = (int*)(base + off);                           off += (size_t)CAP * 4;
    unsigned* mask = (unsigned*)(base + off);                      off += (size_t)NWORD * 4;
    int* wl_cnt    = (int*)(base + off);                           off += (size_t)GRD_PX4 * 4;
    uint2* wl      = (uint2*)(base + off);                         off += (size_t)GRD_PX4 * WLSTRIDE * 8;
    int* ovf       = (int*)(base + off);

    mask_init_k<<<GRD_PX4, BLK, 0, stream>>>(x, parent, mask, wl, wl_cnt, ovf);
    union_k    <<<GRD_W,   BLK, 0, stream>>>(mask, parent);
    claim_k    <<<GRD_W,   BLK, 0, stream>>>(mask, parent, cnt, best, ovf);
    stats_k    <<<GRD_PX4, 64,  0, stream>>>(wl, wl_cnt, parent, cnt, best);
    out_k      <<<GRD_PX4, BLK, 0, stream>>>(mask, parent, cnt, best, o);
}